// Round 4
// baseline (1343.024 us; speedup 1.0000x reference)
//
#include <hip/hip_runtime.h>
#include <hip/hip_fp16.h>

typedef unsigned short us;
using short8 = __attribute__((ext_vector_type(8))) short;
using f32x16 = __attribute__((ext_vector_type(16))) float;

#define B_  4
#define T_  2048
#define C_  2048
#define FF_ 8192
#define M_  (B_*T_)
#define NCH 16
#define LCH (T_/NCH)
#define EPS_WKV 1e-8f
#define NK  (C_/64)   // 32 K-tiles of 64

// ---------- helpers ----------
__device__ __forceinline__ us f2bf(float f) {
  union { float f; unsigned u; } v; v.f = f;
  return (us)((v.u + 0x7fffu + ((v.u >> 16) & 1u)) >> 16);
}

__device__ __forceinline__ void gload_lds16(const void* g, void* l) {
  __builtin_amdgcn_global_load_lds((__attribute__((address_space(1))) void*)(void*)g,
                                   (__attribute__((address_space(3))) void*)l, 16, 0, 0);
}

// ---------- fp32 -> bf16, contiguous (1024 elems / block) ----------
__global__ __launch_bounds__(256)
void cvt_bf16(const float* __restrict__ s, us* __restrict__ d) {
  const int i = (blockIdx.x * 256 + threadIdx.x) * 4;
  const float4 v = *(const float4*)(s + i);
  ushort4 o; o.x = f2bf(v.x); o.y = f2bf(v.y); o.z = f2bf(v.z); o.w = f2bf(v.w);
  *(ushort4*)(d + i) = o;
}

// ---------- fp32 -> bf16, strided source rows (for Wcv column slab) ----------
__global__ __launch_bounds__(256)
void cvt_bf16_str(const float* __restrict__ s, us* __restrict__ d, int srs) {
  const int row = blockIdx.y;
  const int col = (blockIdx.x * 256 + threadIdx.x) * 4;
  const float4 v = *(const float4*)(s + (size_t)row * srs + col);
  ushort4 o; o.x = f2bf(v.x); o.y = f2bf(v.y); o.z = f2bf(v.z); o.w = f2bf(v.w);
  *(ushort4*)(d + (size_t)row * 2048 + col) = o;
}

// ---------- LayerNorm: fp32 in -> bf16 out (+ optional fp32 state row) ----------
template<bool WS>
__global__ __launch_bounds__(256)
void ln_kern(const float* __restrict__ x, const float* __restrict__ g,
             const float* __restrict__ bi, us* __restrict__ y,
             float* __restrict__ state)
{
  const int row = blockIdx.x;
  const int tid = threadIdx.x;
  const float* xr = x + (size_t)row * C_;
  const float4 v0 = ((const float4*)xr)[tid];
  const float4 v1 = ((const float4*)xr)[tid + 256];
  float s  = v0.x + v0.y + v0.z + v0.w + v1.x + v1.y + v1.z + v1.w;
  float sq = v0.x*v0.x + v0.y*v0.y + v0.z*v0.z + v0.w*v0.w
           + v1.x*v1.x + v1.y*v1.y + v1.z*v1.z + v1.w*v1.w;
  #pragma unroll
  for (int o = 32; o > 0; o >>= 1) { s += __shfl_down(s, o, 64); sq += __shfl_down(sq, o, 64); }
  __shared__ float ws_[4], wq_[4];
  if ((tid & 63) == 0) { ws_[tid >> 6] = s; wq_[tid >> 6] = sq; }
  __syncthreads();
  s  = ws_[0] + ws_[1] + ws_[2] + ws_[3];
  sq = wq_[0] + wq_[1] + wq_[2] + wq_[3];
  const float mean = s * (1.f / C_);
  const float rstd = rsqrtf(sq * (1.f / C_) - mean * mean + 1e-5f);
  const float4 g0 = ((const float4*)g)[tid],  g1 = ((const float4*)g)[tid + 256];
  const float4 b0 = ((const float4*)bi)[tid], b1 = ((const float4*)bi)[tid + 256];
  const float o0x = (v0.x - mean) * rstd * g0.x + b0.x;
  const float o0y = (v0.y - mean) * rstd * g0.y + b0.y;
  const float o0z = (v0.z - mean) * rstd * g0.z + b0.z;
  const float o0w = (v0.w - mean) * rstd * g0.w + b0.w;
  const float o1x = (v1.x - mean) * rstd * g1.x + b1.x;
  const float o1y = (v1.y - mean) * rstd * g1.y + b1.y;
  const float o1z = (v1.z - mean) * rstd * g1.z + b1.z;
  const float o1w = (v1.w - mean) * rstd * g1.w + b1.w;
  ushort4 p0; p0.x = f2bf(o0x); p0.y = f2bf(o0y); p0.z = f2bf(o0z); p0.w = f2bf(o0w);
  ushort4 p1; p1.x = f2bf(o1x); p1.y = f2bf(o1y); p1.z = f2bf(o1z); p1.w = f2bf(o1w);
  ((ushort4*)(y + (size_t)row * C_))[tid]       = p0;
  ((ushort4*)(y + (size_t)row * C_))[tid + 256] = p1;
  if (WS && ((row & (T_ - 1)) == (T_ - 2))) {
    float* st = state + (size_t)(row >> 11) * C_;
    const int c0 = tid * 4;
    st[c0 + 0] = o0x; st[c0 + 1] = o0y; st[c0 + 2] = o0z; st[c0 + 3] = o0w;
    st[c0 + 1024 + 0] = o1x; st[c0 + 1024 + 1] = o1y;
    st[c0 + 1024 + 2] = o1z; st[c0 + 1024 + 3] = o1w;
  }
}

// ---------- NT GEMM, 256x256 tile, BK=64, 8 waves, double-buffered,
// 2-phase/K-tile schedule with 32x32x16 MFMA (T2+T3/T4+T5).
// Per phase (one K-half of 32): 12 ds_read_b128 + 4 stage-loads ->
// barrier -> lgkmcnt(0) -> 16 x mfma_32x32x16 (~128cy) -> vmcnt(4) barrier.
// Staging spread (4 loads/phase, round-1 regime); never vmcnt(0) in loop.
//
// LDS map (us units): A: [buf d][kh b][row 0..255][chunk-swizzled 32 cols]
//   A base = d*16384 + b*8192, row stride 32, chunk c' = c ^ ((row>>1)&3)
//   B base = 32768 + same layout. Total 128 KiB.
// Staging: global_load_lds 16B/lane, LDS dest linear (wave base + lane*16);
//   global source pre-swizzled so LDS holds the c' layout (rule 21).
//
// 32x32x16 fragments: A lane l: row=l&31, k=(l>>5)*8+idx (contig 8 bf16);
// B same with col=l&31. C/D: col=l&31, row=(r&3)+8*(r>>2)+4*(l>>5) [m74/m101].

#define STAGE_A(D,KB,KO) do { \
  gload_lds16(gA1 + (KO), &lds[(D)*16384 + (KB)*8192 + sdA]); \
  gload_lds16(gA2 + (KO), &lds[(D)*16384 + (KB)*8192 + sdA + 4096]); } while(0)
#define STAGE_B(D,KB,KO) do { \
  gload_lds16(gB1 + (KO), &lds[(D)*16384 + (KB)*8192 + sdB]); \
  gload_lds16(gB2 + (KO), &lds[(D)*16384 + (KB)*8192 + sdB + 4096]); } while(0)

#define LDA32(MF,D,KB,CC) (*(const short8*)&lds[(D)*16384 + (KB)*8192 + (rA32 + (MF)*32)*32 + (CC)])
#define LDB32(NF,D,KB,CC) (*(const short8*)&lds[32768 + (D)*16384 + (KB)*8192 + (rB32 + (NF)*32)*32 + (CC)])

// read both 16-wide k-slices of K-half KB from buffer D
#define READ_PH(D,KB) do { \
  _Pragma("unroll") for (int _m = 0; _m < 4; _m++) af[_m][0] = LDA32(_m,(D),(KB),cS0); \
  _Pragma("unroll") for (int _m = 0; _m < 4; _m++) af[_m][1] = LDA32(_m,(D),(KB),cS1); \
  bf[0][0] = LDB32(0,(D),(KB),cS0); bf[1][0] = LDB32(1,(D),(KB),cS0); \
  bf[0][1] = LDB32(0,(D),(KB),cS1); bf[1][1] = LDB32(1,(D),(KB),cS1); } while(0)

#define MFMA_PH() do { _Pragma("unroll") \
  for (int _s = 0; _s < 2; _s++) { _Pragma("unroll") \
    for (int _m = 0; _m < 4; _m++) { _Pragma("unroll") \
      for (int _n = 0; _n < 2; _n++) \
        acc[_m][_n] = __builtin_amdgcn_mfma_f32_32x32x16_bf16(af[_m][_s], bf[_n][_s], acc[_m][_n], 0, 0, 0); } } } while(0)

#define PH_PRE() do { \
  __builtin_amdgcn_s_barrier(); \
  __builtin_amdgcn_sched_barrier(0); \
  asm volatile("s_waitcnt lgkmcnt(0)" ::: "memory"); \
  __builtin_amdgcn_sched_barrier(0); \
  __builtin_amdgcn_s_setprio(1); } while(0)

#define PH_POST_VM4() do { \
  __builtin_amdgcn_s_setprio(0); \
  asm volatile("s_waitcnt vmcnt(4)" ::: "memory"); \
  __builtin_amdgcn_s_barrier(); \
  __builtin_amdgcn_sched_barrier(0); } while(0)

template<int MODE>
__global__ __launch_bounds__(512, 2)
void gemm_nt(const us* __restrict__ A, const us* __restrict__ Bw,
             void* __restrict__ out0, void* __restrict__ out1, void* __restrict__ out2,
             const __half* __restrict__ crv, float* __restrict__ fout)
{
  __shared__ __align__(16) us lds[65536];   // 128 KiB
  const int tid  = threadIdx.x;
  const int w    = tid >> 6, l = tid & 63;
  const int l31  = l & 31, hi = l >> 5;
  const int wm = w >> 2, wn = w & 3;        // 2 x 4 wave grid
  const size_t m0 = (size_t)blockIdx.y * 256, n0 = (size_t)blockIdx.x * 256;

  // ds_read geometry (32x32 frags): base rows + swizzled chunk cols
  const int rA32 = wm * 128 + l31;
  const int rB32 = wn * 64  + l31;
  const int sw   = (l31 >> 1) & 3;          // (row>>1)&3, frag-offset-invariant
  const int cS0  = ((hi ^ sw)) * 8;         // k-slice 0: chunk q = hi
  const int cS1  = (((2 + hi) ^ sw)) * 8;   // k-slice 1: chunk q = 2+hi

  // staging geometry: lane l -> row (l>>2), slot (l&3); global chunk pre-swizzled
  const int srow = l >> 2;
  const int scol = ((l & 3) ^ ((l >> 3) & 3)) * 8;
  const us* gA1 = A  + (m0 + (size_t)(w * 16 + srow)) * C_ + scol;
  const us* gA2 = gA1 + (size_t)128 * C_;
  const us* gB1 = Bw + (n0 + (size_t)(w * 16 + srow)) * C_ + scol;
  const us* gB2 = gB1 + (size_t)128 * C_;
  const int sdA = w * 512;                  // wave-uniform LDS staging bases
  const int sdB = 32768 + w * 512;

  f32x16 acc[4][2];
  #pragma unroll
  for (int i = 0; i < 4; i++)
    #pragma unroll
    for (int j = 0; j < 2; j++)
      acc[i][j] = (f32x16)(0.f);

  short8 af[4][2], bf[2][2];

  // prologue: stage K-tile 0 (kh0 pair first, then kh1 pair)
  STAGE_A(0, 0, 0); STAGE_B(0, 0, 0);
  STAGE_A(0, 1, 32); STAGE_B(0, 1, 32);
  asm volatile("s_waitcnt vmcnt(4)" ::: "memory");   // kh0 landed; kh1 in flight
  __builtin_amdgcn_s_barrier();
  __builtin_amdgcn_sched_barrier(0);

  int cur = 0;
  #pragma unroll 1
  for (int kt = 0; kt < NK - 1; ++kt) {
    const int nxt = cur ^ 1;
    const int ko  = (kt + 1) * 64;
    // ---- ph0: K-half 0; stage next-tile kh0 ----
    READ_PH(cur, 0);
    STAGE_A(nxt, 0, ko); STAGE_B(nxt, 0, ko);
    PH_PRE(); MFMA_PH(); PH_POST_VM4();    // drains cur.kh1 (8 -> 4 in flight)
    // ---- ph1: K-half 1; stage next-tile kh1 ----
    READ_PH(cur, 1);
    STAGE_A(nxt, 1, ko + 32); STAGE_B(nxt, 1, ko + 32);
    PH_PRE(); MFMA_PH(); PH_POST_VM4();    // drains nxt.kh0 (8 -> 4 in flight)
    cur = nxt;
  }

  // ---- peeled last tile: no staging; cur.kh1 (4 loads) still in flight ----
  READ_PH(cur, 0);
  PH_PRE(); MFMA_PH();
  __builtin_amdgcn_s_setprio(0);
  asm volatile("s_waitcnt vmcnt(0)" ::: "memory");   // kh1 landed
  __builtin_amdgcn_s_barrier();
  __builtin_amdgcn_sched_barrier(0);
  READ_PH(cur, 1);
  PH_PRE(); MFMA_PH();
  __builtin_amdgcn_s_setprio(0);

  // ---- epilogue (32x32 C/D layout: row=(r&3)+8*(r>>2)+4*hi, col=l31) ----
  const int nb = (int)(n0 >> 11);            // MODE 5: 0=k, 1=v, 2=r
  const size_t ncol0 = n0 - ((size_t)nb << 11);

  #pragma unroll
  for (int mf = 0; mf < 4; mf++) {
    #pragma unroll
    for (int nf = 0; nf < 2; nf++) {
      const size_t nc = (size_t)(wn * 64 + nf * 32 + l31);
      #pragma unroll
      for (int rg = 0; rg < 4; rg++) {
        #pragma unroll
        for (int rj = 0; rj < 4; rj++) {
          const int r = rg * 4 + rj;
          const size_t row = m0 + (size_t)(wm * 128 + mf * 32 + rg * 8 + rj + 4 * hi);
          const size_t rowoff = row * C_;
          const float v = acc[mf][nf][r];
          if (MODE == 1) {
            const float t = v > 0.f ? v : 0.f;
            ((us*)out0)[rowoff + n0 + nc] = f2bf(t * t);
          } else if (MODE == 2) {
            ((__half*)out0)[rowoff + n0 + nc] = __float2half(1.f / (1.f + expf(-v)));
          } else if (MODE == 3) {
            const size_t idx = rowoff + n0 + nc;
            fout[idx] += (float)crv[idx] * v;
          } else { // MODE 5
            const size_t idx = rowoff + ncol0 + nc;
            if (nb == 0)      ((__half*)out0)[idx] = __float2half(v);
            else if (nb == 1) ((__half*)out1)[idx] = __float2half(v);
            else              ((float*)out2)[idx]  = v;
          }
        }
      }
    }
  }
}

// ---------- WKV chunked scan ----------
__global__ __launch_bounds__(256)
void wkv_pass1(const __half* __restrict__ Kh, const __half* __restrict__ Vh,
               const float* __restrict__ tdec, float* __restrict__ chA, float* __restrict__ chB)
{
  const int idx = blockIdx.x * 256 + threadIdx.x;       // over B*NCH*C
  const int c = idx & (C_ - 1);
  const int chunk = (idx >> 11) & (NCH - 1);
  const int b = idx >> 15;
  const float d = expf(-expf(tdec[c]));
  const size_t base = ((size_t)b * T_) * C_ + c;
  float a = 0.f, bb = 0.f;
  const int t0 = chunk * LCH;
  int t = t0;
  if (chunk == 0) { bb = 1.f; t = 1; }                  // t=0: ek=exp(0)=1, v=0
  const int tend = t0 + LCH;
  #pragma unroll 4
  for (; t < tend; ++t) {
    const size_t off = base + (size_t)(t - 1) * C_;
    const float ek = expf((float)Kh[off]);
    const float vv = (float)Vh[off];
    a  = d * a  + ek * vv;
    bb = d * bb + ek;
  }
  chA[idx] = a; chB[idx] = bb;
}

__global__ __launch_bounds__(256)
void wkv_pass2(const float* __restrict__ tdec, float* __restrict__ chA, float* __restrict__ chB)
{
  const int idx = blockIdx.x * 256 + threadIdx.x;       // over B*C
  const int c = idx & (C_ - 1);
  const int b = idx >> 11;
  const float dL = expf(-expf(tdec[c]) * (float)LCH);
  float a = 0.f, bb = 0.f;
  #pragma unroll
  for (int ch = 0; ch < NCH; ++ch) {
    const int s = (b * NCH + ch) * C_ + c;
    const float la = chA[s], lb = chB[s];
    chA[s] = a; chB[s] = bb;                            // incoming state for chunk
    a  = dL * a  + la;
    bb = dL * bb + lb;
  }
}

__global__ __launch_bounds__(256)
void wkv_pass3(const __half* __restrict__ Kh, const __half* __restrict__ Vh,
               const float* __restrict__ xin, const float* __restrict__ tdec,
               const float* __restrict__ chA, const float* __restrict__ chB,
               float* __restrict__ outx)
{
  const int idx = blockIdx.x * 256 + threadIdx.x;       // over B*NCH*C
  const int c = idx & (C_ - 1);
  const int chunk = (idx >> 11) & (NCH - 1);
  const int b = idx >> 15;
  const float d = expf(-expf(tdec[c]));
  const size_t base = ((size_t)b * T_) * C_ + c;
  float a = chA[idx], bb = chB[idx];
  const int t0 = chunk * LCH;
  int t = t0;
  if (chunk == 0) {
    a = d * a;                                          // + 1*0
    bb = d * bb + 1.f;
    const float wkv = a / (bb + EPS_WKV);
    const float r = outx[base];
    outx[base] = xin[base] + r * wkv;
    t = 1;
  }
  const int tend = t0 + LCH;
  #pragma unroll 4
  for (; t < tend; ++t) {
    const size_t offp = base + (size_t)(t - 1) * C_;
    const size_t off  = base + (size_t)t * C_;
    const float ek = expf((float)Kh[offp]);
    const float vv = (float)Vh[offp];
    a  = d * a  + ek * vv;
    bb = d * bb + ek;
    const float wkv = a / (bb + EPS_WKV);
    const float r = outx[off];
    outx[off] = xin[off] + r * wkv;
  }
}

// ---------- launch ----------
extern "C" void kernel_launch(void* const* d_in, const int* in_sizes, int n_in,
                              void* d_out, int out_size, void* d_ws, size_t ws_size,
                              hipStream_t stream)
{
  const float* x    = (const float*)d_in[0];
  const float* ln1g = (const float*)d_in[1];
  const float* ln1b = (const float*)d_in[2];
  const float* tdec = (const float*)d_in[3];
  const float* Wk   = (const float*)d_in[4];
  const float* Wv   = (const float*)d_in[5];
  const float* Wr   = (const float*)d_in[6];
  const float* ln2g = (const float*)d_in[7];
  const float* ln2b = (const float*)d_in[8];
  const float* Wck  = (const float*)d_in[9];
  const float* Wcv  = (const float*)d_in[10];
  const float* Wcr  = (const float*)d_in[11];

  // 145 MiB workspace (phase-disjoint aliases):
  //  [0,32Mi)    xln bf16 M*C          -> later ck_chunk bf16 M*2048
  //  [32,64Mi)   Kb fp16 M*C           -> later x2 bf16 M*C
  //  [64,96Mi)   Vb fp16 M*C           -> later crb fp16 M*C
  //  [96,97Mi)   chA, chB fp32 B*NCH*C
  //  [97,121Mi)  wkvr bf16 6144*2048 (Wk|Wv|Wr converted)
  //  [121,129Mi) wcrb bf16 2048*2048
  //  [129,137Mi) wckc bf16 2048*2048 (per-FF-slab)
  //  [137,145Mi) wcvc bf16 2048*2048 (per-FF-slab)
  char* ws = (char*)d_ws;
  us*     xln  = (us*)(ws);
  __half* Kb   = (__half*)(ws + (32ull  << 20));
  __half* Vb   = (__half*)(ws + (64ull  << 20));
  float*  chA  = (float*)(ws + (96ull << 20));
  float*  chB  = (float*)(ws + (96ull << 20) + 524288ull);
  us*     wkvr = (us*)(ws + (97ull  << 20));
  us*     wcrb = (us*)(ws + (121ull << 20));
  us*     wckc = (us*)(ws + (129ull << 20));
  us*     wcvc = (us*)(ws + (137ull << 20));
  us*     x2   = (us*)Kb;
  __half* crb  = (__half*)Vb;
  us*     ckc  = (us*)xln;

  float* outx = (float*)d_out;
  float* outs = outx + (size_t)M_ * C_;

  const dim3 blk(256);
  const dim3 blkG(512);
  const dim3 gC(C_ / 256, M_ / 256);         // (8, 32)
  const dim3 gKVR(3 * C_ / 256, M_ / 256);   // (24, 32)

  // convert k/v/r/cr weights to bf16 (contiguous, 4M elems each -> 4096 blocks)
  cvt_bf16<<<4096, blk, 0, stream>>>(Wk,  wkvr);
  cvt_bf16<<<4096, blk, 0, stream>>>(Wv,  wkvr + (size_t)C_ * C_);
  cvt_bf16<<<4096, blk, 0, stream>>>(Wr,  wkvr + 2 * (size_t)C_ * C_);
  cvt_bf16<<<4096, blk, 0, stream>>>(Wcr, wcrb);

  // LN1 (+ state = xln row T-2 per batch)
  ln_kern<true><<<M_, blk, 0, stream>>>(x, ln1g, ln1b, xln, outs);

  // fused k|v|r GEMM: N=6144; k,v -> fp16, r -> fp32 straight into d_out
  gemm_nt<5><<<gKVR, blkG, 0, stream>>>(xln, wkvr, (void*)Kb, (void*)Vb, (void*)outx, nullptr, nullptr);

  // chunked WKV scan; pass3 rewrites outx in place: x + r*wkv
  wkv_pass1<<<(B_ * NCH * C_) / 256, blk, 0, stream>>>(Kb, Vb, tdec, chA, chB);
  wkv_pass2<<<(B_ * C_) / 256,       blk, 0, stream>>>(tdec, chA, chB);
  wkv_pass3<<<(B_ * NCH * C_) / 256, blk, 0, stream>>>(Kb, Vb, x, tdec, chA, chB, outx);

  // LN2 -> x2 (bf16)
  ln_kern<false><<<M_, blk, 0, stream>>>(outx, ln2g, ln2b, x2, nullptr);

  // cr = sigmoid(x2 @ Wcr^T) -> fp16
  gemm_nt<2><<<gC, blkG, 0, stream>>>(x2, wcrb, (void*)crb, nullptr, nullptr, nullptr, nullptr);

  // FFN in 4 slabs of 2048: ck = relu(x2 @ Wck_f^T)^2 ; out += cr * (ck @ Wcv_f^T)
  for (int f0 = 0; f0 < FF_; f0 += 2048) {
    cvt_bf16<<<4096, blk, 0, stream>>>(Wck + (size_t)f0 * C_, wckc);
    gemm_nt<1><<<gC, blkG, 0, stream>>>(x2, wckc, (void*)ckc, nullptr, nullptr, nullptr, nullptr);
    cvt_bf16_str<<<dim3(2, 2048), blk, 0, stream>>>(Wcv + f0, wcvc, FF_);
    gemm_nt<3><<<gC, blkG, 0, stream>>>(ckc, wcvc, nullptr, nullptr, nullptr, crb, outx);
  }
}

// Round 5
// 1217.864 us; speedup vs baseline: 1.1028x; 1.1028x over previous
//
#include <hip/hip_runtime.h>
#include <hip/hip_fp16.h>

typedef unsigned short us;
using short8 = __attribute__((ext_vector_type(8))) short;
using f32x4  = __attribute__((ext_vector_type(4))) float;

#define B_  4
#define T_  2048
#define C_  2048
#define FF_ 8192
#define M_  (B_*T_)
#define NCHB 5
#define NCH (1<<NCHB)     // 32 chunks
#define LCH (T_/NCH)      // 64
#define EPS_WKV 1e-8f
#define NK  (C_/64)       // 32 K-tiles of 64

// ---------- helpers ----------
__device__ __forceinline__ us f2bf(float f) {
  union { float f; unsigned u; } v; v.f = f;
  return (us)((v.u + 0x7fffu + ((v.u >> 16) & 1u)) >> 16);
}

__device__ __forceinline__ void gload_lds16(const void* g, void* l) {
  __builtin_amdgcn_global_load_lds((__attribute__((address_space(1))) void*)(void*)g,
                                   (__attribute__((address_space(3))) void*)l, 16, 0, 0);
}

// ---------- fp32 -> bf16, contiguous (1024 elems / block) ----------
__global__ __launch_bounds__(256)
void cvt_bf16(const float* __restrict__ s, us* __restrict__ d) {
  const int i = (blockIdx.x * 256 + threadIdx.x) * 4;
  const float4 v = *(const float4*)(s + i);
  ushort4 o; o.x = f2bf(v.x); o.y = f2bf(v.y); o.z = f2bf(v.z); o.w = f2bf(v.w);
  *(ushort4*)(d + i) = o;
}

// ---------- fp32 -> bf16, strided source rows (for Wcv column slab) ----------
__global__ __launch_bounds__(256)
void cvt_bf16_str(const float* __restrict__ s, us* __restrict__ d, int srs) {
  const int row = blockIdx.y;
  const int col = (blockIdx.x * 256 + threadIdx.x) * 4;
  const float4 v = *(const float4*)(s + (size_t)row * srs + col);
  ushort4 o; o.x = f2bf(v.x); o.y = f2bf(v.y); o.z = f2bf(v.z); o.w = f2bf(v.w);
  *(ushort4*)(d + (size_t)row * 2048 + col) = o;
}

// ---------- LayerNorm: fp32 in -> bf16 out (+ optional fp32 state row) ----------
template<bool WS>
__global__ __launch_bounds__(256)
void ln_kern(const float* __restrict__ x, const float* __restrict__ g,
             const float* __restrict__ bi, us* __restrict__ y,
             float* __restrict__ state)
{
  const int row = blockIdx.x;
  const int tid = threadIdx.x;
  const float* xr = x + (size_t)row * C_;
  const float4 v0 = ((const float4*)xr)[tid];
  const float4 v1 = ((const float4*)xr)[tid + 256];
  float s  = v0.x + v0.y + v0.z + v0.w + v1.x + v1.y + v1.z + v1.w;
  float sq = v0.x*v0.x + v0.y*v0.y + v0.z*v0.z + v0.w*v0.w
           + v1.x*v1.x + v1.y*v1.y + v1.z*v1.z + v1.w*v1.w;
  #pragma unroll
  for (int o = 32; o > 0; o >>= 1) { s += __shfl_down(s, o, 64); sq += __shfl_down(sq, o, 64); }
  __shared__ float ws_[4], wq_[4];
  if ((tid & 63) == 0) { ws_[tid >> 6] = s; wq_[tid >> 6] = sq; }
  __syncthreads();
  s  = ws_[0] + ws_[1] + ws_[2] + ws_[3];
  sq = wq_[0] + wq_[1] + wq_[2] + wq_[3];
  const float mean = s * (1.f / C_);
  const float rstd = rsqrtf(sq * (1.f / C_) - mean * mean + 1e-5f);
  const float4 g0 = ((const float4*)g)[tid],  g1 = ((const float4*)g)[tid + 256];
  const float4 b0 = ((const float4*)bi)[tid], b1 = ((const float4*)bi)[tid + 256];
  const float o0x = (v0.x - mean) * rstd * g0.x + b0.x;
  const float o0y = (v0.y - mean) * rstd * g0.y + b0.y;
  const float o0z = (v0.z - mean) * rstd * g0.z + b0.z;
  const float o0w = (v0.w - mean) * rstd * g0.w + b0.w;
  const float o1x = (v1.x - mean) * rstd * g1.x + b1.x;
  const float o1y = (v1.y - mean) * rstd * g1.y + b1.y;
  const float o1z = (v1.z - mean) * rstd * g1.z + b1.z;
  const float o1w = (v1.w - mean) * rstd * g1.w + b1.w;
  ushort4 p0; p0.x = f2bf(o0x); p0.y = f2bf(o0y); p0.z = f2bf(o0z); p0.w = f2bf(o0w);
  ushort4 p1; p1.x = f2bf(o1x); p1.y = f2bf(o1y); p1.z = f2bf(o1z); p1.w = f2bf(o1w);
  ((ushort4*)(y + (size_t)row * C_))[tid]       = p0;
  ((ushort4*)(y + (size_t)row * C_))[tid + 256] = p1;
  if (WS && ((row & (T_ - 1)) == (T_ - 2))) {
    float* st = state + (size_t)(row >> 11) * C_;
    const int c0 = tid * 4;
    st[c0 + 0] = o0x; st[c0 + 1] = o0y; st[c0 + 2] = o0z; st[c0 + 3] = o0w;
    st[c0 + 1024 + 0] = o1x; st[c0 + 1024 + 1] = o1y;
    st[c0 + 1024 + 2] = o1z; st[c0 + 1024 + 3] = o1w;
  }
}

// ---------- NT GEMM, 256x256 tile, BK=64, 8 waves, double-buffered,
// 2-phase/K-tile counted-vmcnt schedule, 16x16x32 MFMA (round-1 layout).
// Per phase (one K-half of 32): 12 ds_read_b128 (8 A-frags + 4 B-frags) +
// 4 stage-loads -> barrier -> lgkmcnt(0) -> 32 MFMA -> vmcnt(4) -> barrier.
// vs round-1: same reads, same staging, same vmcnt(4) rate, HALF the
// barrier pairs (4/tile vs 8/tile), 32 MFMA per barrier-pair vs 16.
//
// LDS map (us units): A: [buf d][kh b][row 0..255][chunk-swizzled 32 cols]
//   A base = d*16384 + b*8192, row stride 32, chunk c' = c ^ ((row>>1)&3)
//   B base = 32768 + same layout. Total 128 KiB.
// Staging: global_load_lds 16B/lane, LDS dest linear (wave base + lane*16);
//   global source pre-swizzled so LDS holds the c' layout (rule 21).

#define STAGE_A(D,KB,KO) do { \
  gload_lds16(gA1 + (KO), &lds[(D)*16384 + (KB)*8192 + sdA]); \
  gload_lds16(gA2 + (KO), &lds[(D)*16384 + (KB)*8192 + sdA + 4096]); } while(0)
#define STAGE_B(D,KB,KO) do { \
  gload_lds16(gB1 + (KO), &lds[(D)*16384 + (KB)*8192 + sdB]); \
  gload_lds16(gB2 + (KO), &lds[(D)*16384 + (KB)*8192 + sdB + 4096]); } while(0)

#define LDA_(MF,D,KB) (*(const short8*)&lds[(D)*16384 + (KB)*8192 + (rA + (MF)*16)*32 + cA])
#define LDB_(NF,D,KB) (*(const short8*)&lds[32768 + (D)*16384 + (KB)*8192 + (rB + (NF)*16)*32 + cB])

// read all operands of one K-half: 8 A-frags + 4 B-frags (12 x ds_read_b128)
#define READ_PH2(D,KB) do { \
  _Pragma("unroll") for (int _i = 0; _i < 8; _i++) af[_i] = LDA_(_i,(D),(KB)); \
  _Pragma("unroll") for (int _j = 0; _j < 4; _j++) bf[_j] = LDB_(_j,(D),(KB)); } while(0)

#define MFMA32() do { _Pragma("unroll") \
  for (int _i = 0; _i < 8; _i++) { _Pragma("unroll") \
    for (int _j = 0; _j < 4; _j++) \
      acc[_i][_j] = __builtin_amdgcn_mfma_f32_16x16x32_bf16(af[_i], bf[_j], acc[_i][_j], 0, 0, 0); } } while(0)

#define PH_PRE() do { \
  __builtin_amdgcn_s_barrier(); \
  __builtin_amdgcn_sched_barrier(0); \
  asm volatile("s_waitcnt lgkmcnt(0)" ::: "memory"); \
  __builtin_amdgcn_sched_barrier(0); \
  __builtin_amdgcn_s_setprio(1); } while(0)

#define PH_POST_VM4() do { \
  __builtin_amdgcn_s_setprio(0); \
  asm volatile("s_waitcnt vmcnt(4)" ::: "memory"); \
  __builtin_amdgcn_s_barrier(); \
  __builtin_amdgcn_sched_barrier(0); } while(0)

template<int MODE>
__global__ __launch_bounds__(512, 2)
void gemm_nt(const us* __restrict__ A, const us* __restrict__ Bw,
             void* __restrict__ out0, void* __restrict__ out1, void* __restrict__ out2,
             const __half* __restrict__ crv, float* __restrict__ fout)
{
  __shared__ __align__(16) us lds[65536];   // 128 KiB
  const int tid  = threadIdx.x;
  const int w    = tid >> 6, l = tid & 63;
  const int quad = l >> 4, l16 = l & 15;
  const int wm = w >> 2, wn = w & 3;        // 2 x 4 wave grid
  const size_t m0 = (size_t)blockIdx.y * 256, n0 = (size_t)blockIdx.x * 256;

  // ds_read geometry: frag row base + constant swizzled chunk per thread
  const int rA = wm * 128 + l16;
  const int rB = wn * 64  + l16;
  const int cA = (quad ^ ((rA >> 1) & 3)) * 8;
  const int cB = (quad ^ ((rB >> 1) & 3)) * 8;

  // staging geometry: lane l -> row (l>>2), slot (l&3); global chunk pre-swizzled
  const int srow = l >> 2;
  const int scol = ((l & 3) ^ ((l >> 3) & 3)) * 8;
  const us* gA1 = A  + (m0 + (size_t)(w * 16 + srow)) * C_ + scol;
  const us* gA2 = gA1 + (size_t)64 * C_ * 2;
  const us* gB1 = Bw + (n0 + (size_t)(w * 16 + srow)) * C_ + scol;
  const us* gB2 = gB1 + (size_t)64 * C_ * 2;
  const int sdA = w * 512;                  // wave-uniform LDS staging bases
  const int sdB = 32768 + w * 512;

  f32x4 acc[8][4];
  #pragma unroll
  for (int i = 0; i < 8; i++)
    #pragma unroll
    for (int j = 0; j < 4; j++)
      acc[i][j] = (f32x4){0.f, 0.f, 0.f, 0.f};

  short8 af[8], bf[4];

  // prologue: stage K-tile 0 (kh0 pair first, then kh1 pair)
  STAGE_A(0, 0, 0); STAGE_B(0, 0, 0);
  STAGE_A(0, 1, 32); STAGE_B(0, 1, 32);
  asm volatile("s_waitcnt vmcnt(4)" ::: "memory");   // kh0 landed; kh1 in flight
  __builtin_amdgcn_s_barrier();
  __builtin_amdgcn_sched_barrier(0);

  int cur = 0;
  #pragma unroll 1
  for (int kt = 0; kt < NK - 1; ++kt) {
    const int nxt = cur ^ 1;
    const int ko  = (kt + 1) * 64;
    // ---- S0: K-half 0; stage next-tile kh0 ----
    READ_PH2(cur, 0);
    STAGE_A(nxt, 0, ko); STAGE_B(nxt, 0, ko);
    PH_PRE(); MFMA32(); PH_POST_VM4();     // drains cur.kh1 (8 -> 4 in flight)
    // ---- S1: K-half 1; stage next-tile kh1 ----
    READ_PH2(cur, 1);
    STAGE_A(nxt, 1, ko + 32); STAGE_B(nxt, 1, ko + 32);
    PH_PRE(); MFMA32(); PH_POST_VM4();     // drains nxt.kh0 (8 -> 4 in flight)
    cur = nxt;
  }

  // ---- peeled last tile: no staging; cur.kh1 (4 loads) still in flight ----
  READ_PH2(cur, 0);
  PH_PRE(); MFMA32();
  __builtin_amdgcn_s_setprio(0);
  asm volatile("s_waitcnt vmcnt(0)" ::: "memory");   // kh1 landed
  __builtin_amdgcn_s_barrier();
  __builtin_amdgcn_sched_barrier(0);
  READ_PH2(cur, 1);
  PH_PRE(); MFMA32();
  __builtin_amdgcn_s_setprio(0);

  // ---- epilogue (16x16 C/D: col = l16, row = quad*4 + j) ----
  const int nb = (int)(n0 >> 11);            // MODE 5: 0=k, 1=v, 2=r
  const size_t ncol0 = n0 - ((size_t)nb << 11);

  #pragma unroll
  for (int mf = 0; mf < 8; mf++) {
    const size_t rbase = m0 + (size_t)(wm * 128 + mf * 16 + quad * 4);
    #pragma unroll
    for (int j = 0; j < 4; j++) {
      const size_t rowoff = (rbase + j) * C_;
      #pragma unroll
      for (int nf = 0; nf < 4; nf++) {
        const size_t nc = (size_t)(wn * 64 + nf * 16 + l16);
        const float v = acc[mf][nf][j];
        if (MODE == 1) {
          const float t = v > 0.f ? v : 0.f;
          ((us*)out0)[rowoff + n0 + nc] = f2bf(t * t);
        } else if (MODE == 2) {
          ((__half*)out0)[rowoff + n0 + nc] = __float2half(1.f / (1.f + expf(-v)));
        } else if (MODE == 3) {
          const size_t idx = rowoff + n0 + nc;
          fout[idx] += (float)crv[idx] * v;
        } else { // MODE 5
          const size_t idx = rowoff + ncol0 + nc;
          if (nb == 0)      ((__half*)out0)[idx] = __float2half(v);
          else if (nb == 1) ((__half*)out1)[idx] = __float2half(v);
          else              ((float*)out2)[idx]  = v;
        }
      }
    }
  }
}

// ---------- WKV chunked scan (NCH=32 -> 64-iter serial chains) ----------
__global__ __launch_bounds__(256)
void wkv_pass1(const __half* __restrict__ Kh, const __half* __restrict__ Vh,
               const float* __restrict__ tdec, float* __restrict__ chA, float* __restrict__ chB)
{
  const int idx = blockIdx.x * 256 + threadIdx.x;       // over B*NCH*C
  const int c = idx & (C_ - 1);
  const int chunk = (idx >> 11) & (NCH - 1);
  const int b = idx >> (11 + NCHB);
  const float d = expf(-expf(tdec[c]));
  const size_t base = ((size_t)b * T_) * C_ + c;
  float a = 0.f, bb = 0.f;
  const int t0 = chunk * LCH;
  int t = t0;
  if (chunk == 0) { bb = 1.f; t = 1; }                  // t=0: ek=exp(0)=1, v=0
  const int tend = t0 + LCH;
  #pragma unroll 4
  for (; t < tend; ++t) {
    const size_t off = base + (size_t)(t - 1) * C_;
    const float ek = expf((float)Kh[off]);
    const float vv = (float)Vh[off];
    a  = d * a  + ek * vv;
    bb = d * bb + ek;
  }
  chA[idx] = a; chB[idx] = bb;
}

__global__ __launch_bounds__(256)
void wkv_pass2(const float* __restrict__ tdec, float* __restrict__ chA, float* __restrict__ chB)
{
  const int idx = blockIdx.x * 256 + threadIdx.x;       // over B*C
  const int c = idx & (C_ - 1);
  const int b = idx >> 11;
  const float dL = expf(-expf(tdec[c]) * (float)LCH);
  float a = 0.f, bb = 0.f;
  #pragma unroll
  for (int ch = 0; ch < NCH; ++ch) {
    const int s = (b * NCH + ch) * C_ + c;
    const float la = chA[s], lb = chB[s];
    chA[s] = a; chB[s] = bb;                            // incoming state for chunk
    a  = dL * a  + la;
    bb = dL * bb + lb;
  }
}

__global__ __launch_bounds__(256)
void wkv_pass3(const __half* __restrict__ Kh, const __half* __restrict__ Vh,
               const float* __restrict__ xin, const float* __restrict__ tdec,
               const float* __restrict__ chA, const float* __restrict__ chB,
               float* __restrict__ outx)
{
  const int idx = blockIdx.x * 256 + threadIdx.x;       // over B*NCH*C
  const int c = idx & (C_ - 1);
  const int chunk = (idx >> 11) & (NCH - 1);
  const int b = idx >> (11 + NCHB);
  const float d = expf(-expf(tdec[c]));
  const size_t base = ((size_t)b * T_) * C_ + c;
  float a = chA[idx], bb = chB[idx];
  const int t0 = chunk * LCH;
  int t = t0;
  if (chunk == 0) {
    a = d * a;                                          // + 1*0
    bb = d * bb + 1.f;
    const float wkv = a / (bb + EPS_WKV);
    const float r = outx[base];
    outx[base] = xin[base] + r * wkv;
    t = 1;
  }
  const int tend = t0 + LCH;
  #pragma unroll 4
  for (; t < tend; ++t) {
    const size_t offp = base + (size_t)(t - 1) * C_;
    const size_t off  = base + (size_t)t * C_;
    const float ek = expf((float)Kh[offp]);
    const float vv = (float)Vh[offp];
    a  = d * a  + ek * vv;
    bb = d * bb + ek;
    const float wkv = a / (bb + EPS_WKV);
    const float r = outx[off];
    outx[off] = xin[off] + r * wkv;
  }
}

// ---------- launch ----------
extern "C" void kernel_launch(void* const* d_in, const int* in_sizes, int n_in,
                              void* d_out, int out_size, void* d_ws, size_t ws_size,
                              hipStream_t stream)
{
  const float* x    = (const float*)d_in[0];
  const float* ln1g = (const float*)d_in[1];
  const float* ln1b = (const float*)d_in[2];
  const float* tdec = (const float*)d_in[3];
  const float* Wk   = (const float*)d_in[4];
  const float* Wv   = (const float*)d_in[5];
  const float* Wr   = (const float*)d_in[6];
  const float* ln2g = (const float*)d_in[7];
  const float* ln2b = (const float*)d_in[8];
  const float* Wck  = (const float*)d_in[9];
  const float* Wcv  = (const float*)d_in[10];
  const float* Wcr  = (const float*)d_in[11];

  // 145 MiB workspace (phase-disjoint aliases):
  //  [0,32Mi)    xln bf16 M*C          -> later ck_chunk bf16 M*2048
  //  [32,64Mi)   Kb fp16 M*C           -> later x2 bf16 M*C
  //  [64,96Mi)   Vb fp16 M*C           -> later crb fp16 M*C
  //  [97,121Mi)  wkvr bf16 6144*2048 (Wk|Wv|Wr) -> first 2MiB reused as chA/chB
  //  [121,129Mi) wcrb bf16 2048*2048
  //  [129,137Mi) wckc bf16 2048*2048 (per-FF-slab)
  //  [137,145Mi) wcvc bf16 2048*2048 (per-FF-slab)
  char* ws = (char*)d_ws;
  us*     xln  = (us*)(ws);
  __half* Kb   = (__half*)(ws + (32ull  << 20));
  __half* Vb   = (__half*)(ws + (64ull  << 20));
  us*     wkvr = (us*)(ws + (97ull  << 20));
  float*  chA  = (float*)(ws + (97ull << 20));           // aliases wkvr[0,1Mi) -- free after kvr GEMM
  float*  chB  = (float*)(ws + (98ull << 20));           // aliases wkvr[1,2Mi)
  us*     wcrb = (us*)(ws + (121ull << 20));
  us*     wckc = (us*)(ws + (129ull << 20));
  us*     wcvc = (us*)(ws + (137ull << 20));
  us*     x2   = (us*)Kb;
  __half* crb  = (__half*)Vb;
  us*     ckc  = (us*)xln;

  float* outx = (float*)d_out;
  float* outs = outx + (size_t)M_ * C_;

  const dim3 blk(256);
  const dim3 blkG(512);
  const dim3 gC(C_ / 256, M_ / 256);         // (8, 32)
  const dim3 gKVR(3 * C_ / 256, M_ / 256);   // (24, 32)

  // convert k/v/r/cr weights to bf16 (contiguous, 4M elems each -> 4096 blocks)
  cvt_bf16<<<4096, blk, 0, stream>>>(Wk,  wkvr);
  cvt_bf16<<<4096, blk, 0, stream>>>(Wv,  wkvr + (size_t)C_ * C_);
  cvt_bf16<<<4096, blk, 0, stream>>>(Wr,  wkvr + 2 * (size_t)C_ * C_);
  cvt_bf16<<<4096, blk, 0, stream>>>(Wcr, wcrb);

  // LN1 (+ state = xln row T-2 per batch)
  ln_kern<true><<<M_, blk, 0, stream>>>(x, ln1g, ln1b, xln, outs);

  // fused k|v|r GEMM: N=6144; k,v -> fp16, r -> fp32 straight into d_out
  gemm_nt<5><<<gKVR, blkG, 0, stream>>>(xln, wkvr, (void*)Kb, (void*)Vb, (void*)outx, nullptr, nullptr);

  // chunked WKV scan; pass3 rewrites outx in place: x + r*wkv
  wkv_pass1<<<(B_ * NCH * C_) / 256, blk, 0, stream>>>(Kb, Vb, tdec, chA, chB);
  wkv_pass2<<<(B_ * C_) / 256,       blk, 0, stream>>>(tdec, chA, chB);
  wkv_pass3<<<(B_ * NCH * C_) / 256, blk, 0, stream>>>(Kb, Vb, x, tdec, chA, chB, outx);

  // LN2 -> x2 (bf16)
  ln_kern<false><<<M_, blk, 0, stream>>>(outx, ln2g, ln2b, x2, nullptr);

  // cr = sigmoid(x2 @ Wcr^T) -> fp16
  gemm_nt<2><<<gC, blkG, 0, stream>>>(x2, wcrb, (void*)crb, nullptr, nullptr, nullptr, nullptr);

  // FFN in 4 slabs of 2048: ck = relu(x2 @ Wck_f^T)^2 ; out += cr * (ck @ Wcv_f^T)
  for (int f0 = 0; f0 < FF_; f0 += 2048) {
    cvt_bf16<<<4096, blk, 0, stream>>>(Wck + (size_t)f0 * C_, wckc);
    gemm_nt<1><<<gC, blkG, 0, stream>>>(x2, wckc, (void*)ckc, nullptr, nullptr, nullptr, nullptr);
    cvt_bf16_str<<<dim3(2, 2048), blk, 0, stream>>>(Wcv + f0, wcvc, FF_);
    gemm_nt<3><<<gC, blkG, 0, stream>>>(ckc, wcvc, nullptr, nullptr, nullptr, crb, outx);
  }
}